// Round 11
// baseline (304.305 us; speedup 1.0000x reference)
//
#include <hip/hip_runtime.h>

#define NE 8
#define CAP 1024
#define HD 1024
#define ID 1408
#define TT 2048

typedef __attribute__((ext_vector_type(8))) short bf16x8;
typedef __attribute__((ext_vector_type(4))) float f32x4;
typedef unsigned short u16;
typedef unsigned int u32;
typedef unsigned long long u64;

__device__ __forceinline__ u16 f2bf(float f) {
  u32 u = __float_as_uint(f);
  u = (u + 0x7fffu + ((u >> 16) & 1u)) >> 16;
  return (u16)u;
}
__device__ __forceinline__ ushort4 cvt4(float4 v) {
  ushort4 o;
  o.x = f2bf(v.x); o.y = f2bf(v.y); o.z = f2bf(v.z); o.w = f2bf(v.w);
  return o;
}

__device__ __forceinline__ void async_cp16(const void* g, void* l) {
  __builtin_amdgcn_global_load_lds(
      (const __attribute__((address_space(1))) u32*)g,
      (__attribute__((address_space(3))) u32*)l, 16, 0, 0);
}

// pack 8 fp32 (two f32x4) -> bf16x8 by truncation: 1 v_perm_b32 per pair.
__device__ __forceinline__ bf16x8 pack_bf16_trunc(f32x4 lo, f32x4 hi) {
  union { u32 u[4]; bf16x8 v; } r;
  r.u[0] = __builtin_amdgcn_perm(__float_as_uint(lo[1]), __float_as_uint(lo[0]), 0x07060302u);
  r.u[1] = __builtin_amdgcn_perm(__float_as_uint(lo[3]), __float_as_uint(lo[2]), 0x07060302u);
  r.u[2] = __builtin_amdgcn_perm(__float_as_uint(hi[1]), __float_as_uint(hi[0]), 0x07060302u);
  r.u[3] = __builtin_amdgcn_perm(__float_as_uint(hi[3]), __float_as_uint(hi[2]), 0x07060302u);
  return r.v;
}

// ---------------- tiny prep: x fp32->bf16 + out zero (~12 MB) ----------------
#define XB 512
__global__ __launch_bounds__(256) void prep_x_kernel(
    const float4* __restrict__ x, ushort4* __restrict__ bx, float4* __restrict__ out) {
  int t = blockIdx.x * 256 + threadIdx.x;
  const int stride = XB * 256;
#pragma unroll
  for (int k = 0; k < 4; ++k) {   // 512*256*4 == TT*HD/4
    int i = t + k * stride;
    bx[i] = cvt4(x[i]);
    out[i] = float4{0.f, 0.f, 0.f, 0.f};
  }
}

// ---------------- routing: exact flat-order cumsum positions ----------------
__global__ void route_kernel(const int* __restrict__ ids, int* __restrict__ rowmap,
                             int* __restrict__ flatpos, int* __restrict__ counts) {
  __shared__ int ids_s[TT * 2];
  __shared__ int sc[256][NE + 1];
  int tid = threadIdx.x;
  for (int i = tid; i < TT * 2; i += 256) ids_s[i] = ids[i];
  __syncthreads();
  int base = tid * 16;
  u64 own64 = 0;
#pragma unroll
  for (int j = 0; j < 16; ++j) own64 += 1ull << (ids_s[base + j] * 8);
  int own[NE];
#pragma unroll
  for (int e = 0; e < NE; ++e) { own[e] = (int)((own64 >> (e * 8)) & 0xff); sc[tid][e] = own[e]; }
  __syncthreads();
  for (int off = 1; off < 256; off <<= 1) {
    int v[NE];
    if (tid >= off) {
#pragma unroll
      for (int e = 0; e < NE; ++e) v[e] = sc[tid - off][e];
    }
    __syncthreads();
    if (tid >= off) {
#pragma unroll
      for (int e = 0; e < NE; ++e) sc[tid][e] += v[e];
    }
    __syncthreads();
  }
  if (tid == 255) {
#pragma unroll
    for (int e = 0; e < NE; ++e) counts[e] = sc[255][e] < CAP ? sc[255][e] : CAP;
  }
  int excl[NE];
#pragma unroll
  for (int e = 0; e < NE; ++e) excl[e] = sc[tid][e] - own[e];
  __syncthreads();
#pragma unroll
  for (int e = 0; e < NE; ++e) sc[tid][e] = excl[e];
#pragma unroll
  for (int j = 0; j < 16; ++j) {
    int f = base + j;
    int e = ids_s[f];
    int p = sc[tid][e]++;
    if (p < CAP) { rowmap[e * CAP + p] = f; flatpos[f] = p; }
    else flatpos[f] = -1;
  }
}

// ------ GEMM1: gathered x(bf16) . w1(fp32 direct)^T, fused SiLU, 64x128 ------
// A staged bf16 async (8KB); B staged FP32 async via global_load_lds (32KB,
// 8 rounds) — no VGPR round-trip (R8's failure). Conversion to bf16 happens at
// fragment-read (2x ds_read_b128 + 4 v_perm truncation) in the compute phase.
// B LDS row = 64 fp32 = 16 chunks of 16B; chunk swizzle c = p ^ (row&14) keeps
// the 8-float fragment as two ADJACENT chunks (bit0 preserved) and spreads
// banks so conflicts are <=2-way (free, m136).
// Gate/up group-16 interleave applied via B row mapping at staging:
//   nIl -> orig w1 row: grp=nIl>>5, w=nIl&31, w<16 ? grp*16+w : ID+grp*16+w-16
// so acc[ni even]=gate, acc[ni odd]=up for the SAME output in the SAME lane.
__global__ __launch_bounds__(256) void gemm1_kernel(
    const u16* __restrict__ A, const float* __restrict__ W1, u16* __restrict__ Hb,
    const int* __restrict__ rowmap, const int* __restrict__ counts) {
  int e = blockIdx.x;
  int count = counts[e];
  int m0 = blockIdx.y * 64;
  if (m0 >= count) return;
  int n0 = blockIdx.z * 128;
  int tid = threadIdx.x;
  int lane = tid & 63, wid = tid >> 6;
  int wm = wid >> 1, wn = wid & 1;
  int q = lane >> 4, lm = lane & 15;

  __shared__ __align__(16) char smA[64 * 128];    // 8 KB bf16
  __shared__ __align__(16) char smB[128 * 256];   // 32 KB fp32

  // A: bf16, row = tid>>3, chunk-of-8-bf16 swizzled by ^(row&7)
  int rlocA = tid >> 3;
  int chsA = ((tid & 7) ^ (rlocA & 7)) * 8;
  const u16* aP[2];
#pragma unroll
  for (int i = 0; i < 2; ++i) {
    int gr = m0 + rlocA + 32 * i;
    int f = (gr < count) ? rowmap[e * CAP + gr] : 0;
    aP[i] = A + (size_t)(f >> 1) * HD + chsA;
  }
  // B: fp32, 8 rounds; round i covers rows i*16+(tid>>4), chunk c swizzled
  const float* bP[8];
#pragma unroll
  for (int i = 0; i < 8; ++i) {
    int rB = i * 16 + (tid >> 4);
    int nIl = n0 + rB;
    int grp = nIl >> 5, w = nIl & 31;
    int orig = (w < 16) ? (grp * 16 + w) : (ID + grp * 16 + (w - 16));
    int c = (tid & 15) ^ (rB & 14);
    bP[i] = W1 + ((size_t)e * 2 * ID + orig) * HD + c * 4;
  }

  f32x4 zero = {0.f, 0.f, 0.f, 0.f};
  f32x4 acc[2][4];
#pragma unroll
  for (int mi = 0; mi < 2; ++mi)
#pragma unroll
    for (int ni = 0; ni < 4; ++ni) acc[mi][ni] = zero;

  for (int kt = 0; kt < HD / 64; ++kt) {
    int ko = kt * 64;
#pragma unroll
    for (int i = 0; i < 2; ++i)
      async_cp16(aP[i] + ko, smA + (i * 256 + tid) * 16);
#pragma unroll
    for (int i = 0; i < 8; ++i)
      async_cp16(bP[i] + ko, smB + (i * 256 + tid) * 16);
    asm volatile("s_waitcnt vmcnt(0)" ::: "memory");
    __syncthreads();
#pragma unroll
    for (int s = 0; s < 2; ++s) {
      int j = s * 4 + q;
      bf16x8 af[2], bfr[4];
#pragma unroll
      for (int mi = 0; mi < 2; ++mi) {
        int row = wm * 32 + mi * 16 + lm;
        af[mi] = *(const bf16x8*)(smA + row * 128 + ((j ^ (lm & 7)) * 16));
      }
#pragma unroll
      for (int ni = 0; ni < 4; ++ni) {
        int rB = wn * 64 + ni * 16 + lm;
        int pp = (2 * j) ^ (rB & 14);
        const char* bp = smB + rB * 256 + pp * 16;
        f32x4 lo = *(const f32x4*)bp;
        f32x4 hi = *(const f32x4*)(bp + 16);
        bfr[ni] = pack_bf16_trunc(lo, hi);
      }
#pragma unroll
      for (int mi = 0; mi < 2; ++mi)
#pragma unroll
        for (int ni = 0; ni < 4; ++ni)
          acc[mi][ni] = __builtin_amdgcn_mfma_f32_16x16x32_bf16(af[mi], bfr[ni], acc[mi][ni], 0, 0, 0);
    }
    __syncthreads();
  }

  // ---- fused SiLU epilogue: merged 64x64 u16 tile via LDS repack ----
  u16* smOut = (u16*)smB;  // [64][72] u16
#pragma unroll
  for (int mi = 0; mi < 2; ++mi) {
#pragma unroll
    for (int k = 0; k < 2; ++k) {
      int colL = wn * 32 + k * 16 + lm;
#pragma unroll
      for (int r = 0; r < 4; ++r) {
        float g = acc[mi][2 * k][r];
        float u = acc[mi][2 * k + 1][r];
        float a = g / (1.f + __expf(-g)) * u;
        int row = wm * 32 + mi * 16 + q * 4 + r;
        smOut[row * 72 + colL] = f2bf(a);
      }
    }
  }
  __syncthreads();
  {
    int row = tid >> 2, seg = tid & 3;
    const u16* sp = smOut + row * 72 + seg * 16;
    bf16x8 v0 = *(const bf16x8*)sp;
    bf16x8 v1 = *(const bf16x8*)(sp + 8);
    u16* dp = Hb + ((size_t)e * CAP + m0 + row) * ID + (n0 >> 1) + seg * 16;
    *(bf16x8*)dp = v0;
    *(bf16x8*)(dp + 8) = v1;
  }
}

// --- GEMM2: act(bf16) . w2(fp32 direct)^T, fused combine (atomicAdd), 64x64 ---
// Same fp32-B-staging scheme: 16KB fp32 smB, 4 rounds, fragment-read cvt.
__global__ __launch_bounds__(256) void gemm2_kernel(
    const u16* __restrict__ A, const float* __restrict__ W2, float* __restrict__ out,
    const int* __restrict__ rowmap, const int* __restrict__ counts,
    const float* __restrict__ tw) {
  int e = blockIdx.x;
  int count = counts[e];
  int m0 = blockIdx.y * 64;
  if (m0 >= count) return;
  int n0 = blockIdx.z * 64;
  int tid = threadIdx.x;
  int lane = tid & 63, wid = tid >> 6;
  int wm = wid >> 1, wn = wid & 1;
  int q = lane >> 4, lm = lane & 15;

  __shared__ __align__(16) char smA[64 * 128];  // 8 KB bf16
  __shared__ __align__(16) char smB[64 * 256];  // 16 KB fp32

  int rlocA = tid >> 3;
  int chsA = ((tid & 7) ^ (rlocA & 7)) * 8;
  const u16* aP[2];
#pragma unroll
  for (int i = 0; i < 2; ++i)
    aP[i] = A + ((size_t)e * CAP + m0 + rlocA + 32 * i) * ID + chsA;
  const float* bP[4];
#pragma unroll
  for (int i = 0; i < 4; ++i) {
    int rB = i * 16 + (tid >> 4);
    int c = (tid & 15) ^ (rB & 14);
    bP[i] = W2 + ((size_t)e * HD + n0 + rB) * ID + c * 4;
  }

  f32x4 zero = {0.f, 0.f, 0.f, 0.f};
  f32x4 acc[2][2];
#pragma unroll
  for (int mi = 0; mi < 2; ++mi)
#pragma unroll
    for (int ni = 0; ni < 2; ++ni) acc[mi][ni] = zero;

  for (int kt = 0; kt < ID / 64; ++kt) {
    int ko = kt * 64;
#pragma unroll
    for (int i = 0; i < 2; ++i)
      async_cp16(aP[i] + ko, smA + (i * 256 + tid) * 16);
#pragma unroll
    for (int i = 0; i < 4; ++i)
      async_cp16(bP[i] + ko, smB + (i * 256 + tid) * 16);
    asm volatile("s_waitcnt vmcnt(0)" ::: "memory");
    __syncthreads();
#pragma unroll
    for (int s = 0; s < 2; ++s) {
      int j = s * 4 + q;
      bf16x8 af[2], bfr[2];
#pragma unroll
      for (int mi = 0; mi < 2; ++mi) {
        int row = wm * 32 + mi * 16 + lm;
        af[mi] = *(const bf16x8*)(smA + row * 128 + ((j ^ (lm & 7)) * 16));
      }
#pragma unroll
      for (int ni = 0; ni < 2; ++ni) {
        int rB = wn * 32 + ni * 16 + lm;
        int pp = (2 * j) ^ (rB & 14);
        const char* bp = smB + rB * 256 + pp * 16;
        f32x4 lo = *(const f32x4*)bp;
        f32x4 hi = *(const f32x4*)(bp + 16);
        bfr[ni] = pack_bf16_trunc(lo, hi);
      }
#pragma unroll
      for (int mi = 0; mi < 2; ++mi)
#pragma unroll
        for (int ni = 0; ni < 2; ++ni)
          acc[mi][ni] = __builtin_amdgcn_mfma_f32_16x16x32_bf16(af[mi], bfr[ni], acc[mi][ni], 0, 0, 0);
    }
    __syncthreads();
  }

  // fused combine epilogue: out[token, col] += w * y
#pragma unroll
  for (int mi = 0; mi < 2; ++mi) {
#pragma unroll
    for (int r = 0; r < 4; ++r) {
      int grow = m0 + wm * 32 + mi * 16 + q * 4 + r;
      if (grow < count) {
        int f = rowmap[e * CAP + grow];
        float w = tw[f];
        int t = f >> 1;
#pragma unroll
        for (int ni = 0; ni < 2; ++ni) {
          int col = n0 + wn * 32 + ni * 16 + lm;
          atomicAdd(&out[(size_t)t * HD + col], w * acc[mi][ni][r]);
        }
      }
    }
  }
}

extern "C" void kernel_launch(void* const* d_in, const int* in_sizes, int n_in,
                              void* d_out, int out_size, void* d_ws, size_t ws_size,
                              hipStream_t stream) {
  const float* hidden = (const float*)d_in[0];
  const float* w1 = (const float*)d_in[1];
  const float* w2 = (const float*)d_in[2];
  const float* tw = (const float*)d_in[3];
  const int* ids = (const int*)d_in[4];
  float* out = (float*)d_out;

  char* p = (char*)d_ws;
  auto alloc = [&](size_t b) { char* r = p; p += (b + 255) & ~(size_t)255; return r; };
  u16* bx = (u16*)alloc((size_t)TT * HD * 2);          // 4.2 MB
  u16* hbuf = (u16*)alloc((size_t)NE * CAP * ID * 2);  // 23.1 MB
  int* rowmap = (int*)alloc((size_t)NE * CAP * 4);
  int* flatpos = (int*)alloc((size_t)TT * 2 * 4);
  int* counts = (int*)alloc((size_t)NE * 4);

  prep_x_kernel<<<XB, 256, 0, stream>>>((const float4*)hidden, (ushort4*)bx, (float4*)out);

  route_kernel<<<1, 256, 0, stream>>>(ids, rowmap, flatpos, counts);

  // GEMM1 + SiLU (fp32 w1 direct): hbuf = silu(x.w1g^T) * (x.w1u^T)
  gemm1_kernel<<<dim3(NE, CAP / 64, 2 * ID / 128), 256, 0, stream>>>(
      bx, w1, hbuf, rowmap, counts);

  // GEMM2 + combine (fp32 w2 direct): out[t,:] += w * (act . w2^T)
  gemm2_kernel<<<dim3(NE, CAP / 64, HD / 64), 256, 0, stream>>>(
      hbuf, w2, out, rowmap, counts, tw);
}